// Round 3
// baseline (41.109 us; speedup 1.0000x reference)
//
#include <hip/hip_runtime.h>
#include <math.h>

// GENPool: segment softmax aggregation (batch sorted), then s*n/(1+beta*(n-1)).
// out[b][f] = (sum_i x[i][f]*exp(p*x[i][f] - m_bf)) / (sum_i exp(p*x[i][f] - m_bf))
//             * n_b / (1 + beta*(n_b - 1))        over rows i with batch[i]==b.

constexpr int F = 256;        // feature dim (fixed by problem)
constexpr int SPLITS = 4;     // row-parallel splits per block
constexpr int BLOCK = F * SPLITS;  // 1024 threads = 16 waves; 2 blocks/CU = 32 waves/CU

// online-softmax accumulate of one value v into (m, d, s)
#define PROC(v)                                                   \
    do {                                                          \
        float a_  = p * (v);                                      \
        float mn_ = fmaxf(m, a_);                                 \
        float c_  = __expf(m - mn_);  /* exp(-inf)=0 first iter */\
        float w_  = __expf(a_ - mn_);                             \
        d = fmaf(d, c_, w_);                                      \
        s = fmaf(s, c_, (v) * w_);                                \
        m = mn_;                                                  \
    } while (0)

__global__ __launch_bounds__(BLOCK, 2) void genpool_kernel(
    const float* __restrict__ x,
    const int*   __restrict__ batch,
    const float* __restrict__ p_ptr,
    const float* __restrict__ beta_ptr,
    float*       __restrict__ out,
    int N)
{
    const int b     = blockIdx.x;
    const int tid   = threadIdx.x;
    const int f     = tid & (F - 1);
    const int split = tid >> 8;   // F == 256

    const float p    = p_ptr[0];
    const float beta = beta_ptr[0];

    // Interleaved dual binary search over sorted batch:
    //   start = lower_bound(b), end = lower_bound(b+1).
    // Two independent loads per round -> latencies overlap.
    int lo0 = 0, hi0 = N, lo1 = 0, hi1 = N;
    while (lo0 < hi0 || lo1 < hi1) {
        int m0 = (lo0 + hi0) >> 1;
        int m1 = (lo1 + hi1) >> 1;
        int v0 = 0, v1 = 0;
        if (lo0 < hi0) v0 = batch[m0];
        if (lo1 < hi1) v1 = batch[m1];
        if (lo0 < hi0) { if (v0 < b)     lo0 = m0 + 1; else hi0 = m0; }
        if (lo1 < hi1) { if (v1 < b + 1) lo1 = m1 + 1; else hi1 = m1; }
    }
    const int start = lo0;
    const int end   = lo1;

    // Per-thread online softmax over rows start+split, start+split+4, ...
    float m = -INFINITY, d = 0.f, s = 0.f;

    int i = start + split;
    // 4-deep manual load batching: 4 independent loads in flight per thread.
    for (; i + 3 * SPLITS < end; i += 4 * SPLITS) {
        float v0 = x[(size_t)(i + 0 * SPLITS) * F + f];
        float v1 = x[(size_t)(i + 1 * SPLITS) * F + f];
        float v2 = x[(size_t)(i + 2 * SPLITS) * F + f];
        float v3 = x[(size_t)(i + 3 * SPLITS) * F + f];
        PROC(v0); PROC(v1); PROC(v2); PROC(v3);
    }
    for (; i < end; i += SPLITS) {
        float v = x[(size_t)i * F + f];
        PROC(v);
    }

    // Merge the 4 row-splits per feature via LDS (12 KB).
    __shared__ float sm[SPLITS][F];
    __shared__ float sd[SPLITS][F];
    __shared__ float ss[SPLITS][F];
    sm[split][f] = m;
    sd[split][f] = d;
    ss[split][f] = s;
    __syncthreads();

    if (split == 0) {
        float M = sm[0][f];
#pragma unroll
        for (int k = 1; k < SPLITS; ++k) M = fmaxf(M, sm[k][f]);
        float D = 0.f, S = 0.f;
#pragma unroll
        for (int k = 0; k < SPLITS; ++k) {
            float c = __expf(sm[k][f] - M);  // empty split: exp(-inf - M) = 0
            D = fmaf(sd[k][f], c, D);
            S = fmaf(ss[k][f], c, S);
        }

        const float cnt = (float)(end - start);
        float val = 0.f;
        if (cnt > 0.f) {
            float sref = S / D;                      // softmax-weighted mean
            val = sref * cnt / (1.f + beta * (cnt - 1.f));
        }
        out[(size_t)b * F + f] = val;
    }
}

extern "C" void kernel_launch(void* const* d_in, const int* in_sizes, int n_in,
                              void* d_out, int out_size, void* d_ws, size_t ws_size,
                              hipStream_t stream)
{
    const float* x     = (const float*)d_in[0];
    const int*   batch = (const int*)d_in[1];
    const float* p     = (const float*)d_in[2];
    const float* beta  = (const float*)d_in[3];
    float* out = (float*)d_out;

    const int N = in_sizes[1];        // 200000 rows
    const int B = out_size / F;       // 512 segments

    genpool_kernel<<<B, BLOCK, 0, stream>>>(x, batch, p, beta, out, N);
}